// Round 11
// baseline (138.556 us; speedup 1.0000x reference)
//
#include <hip/hip_runtime.h>

typedef _Float16 f16;
typedef _Float16 f16x2 __attribute__((ext_vector_type(2)));
typedef _Float16 f16x4 __attribute__((ext_vector_type(4)));
typedef _Float16 f16x8 __attribute__((ext_vector_type(8)));
typedef float    f32x4 __attribute__((ext_vector_type(4)));

constexpr int B_ = 2, H_ = 16, T_ = 2048, D_ = 64, R_ = 32, NT = 32;
constexpr int NROW = B_ * H_ * T_;   // 65536 (bh,t) rows

__device__ __forceinline__ f32x4 mfma16(f16x8 a, f16x8 b, f32x4 c) {
  return __builtin_amdgcn_mfma_f32_16x16x32_f16(a, b, c, 0, 0, 0);
}
__device__ __forceinline__ void ld_lds16(const void* g, void* l) {
  __builtin_amdgcn_global_load_lds(
      (const __attribute__((address_space(1))) unsigned int*)g,
      (__attribute__((address_space(3))) unsigned int*)l, 16, 0, 0);
}

// ---------------- Kernel A: MFMA projections + swizzled V^T (R7 verbatim) ----------------
__global__ __launch_bounds__(256) void proj_kernel(
    const float* __restrict__ q, const float* __restrict__ k, const float* __restrict__ v,
    const float* __restrict__ Wq, const float* __restrict__ Wk,
    const float* __restrict__ c1, const float* __restrict__ c2,
    f16* __restrict__ qlr, f16* __restrict__ klr, f16* __restrict__ vt)
{
  __shared__ float sv[64 * 65];                    // 16.6 KB V transpose
  __shared__ __align__(16) f16 s_w[2][32 * 64];    //  8 KB W^T [mat][r][d-swz]
  __shared__ __align__(16) f16 s_qk[2][64 * 32];   //  8 KB [mat][row][r]

  const int tid = threadIdx.x, w = tid >> 6, lane = tid & 63;
  const int l15 = lane & 15, l4 = lane >> 4;
  const int bh = blockIdx.x >> 5, h = bh & (H_ - 1);
  const int t0 = (blockIdx.x & 31) * 64;

  const float* vb = v + ((size_t)bh * T_ + t0) * D_;
  float4 vld[4];
#pragma unroll
  for (int it = 0; it < 4; ++it) vld[it] = ((const float4*)vb)[it * 256 + tid];

  const int m = t0 + 16 * w + l15;
  const float* qr = q + ((size_t)bh * T_ + m) * D_;
  const float* kr = k + ((size_t)bh * T_ + m) * D_;
  f16x8 aq[2], ak[2];
#pragma unroll
  for (int kc = 0; kc < 2; ++kc) {
    float4 x0 = *(const float4*)(qr + kc * 32 + 8 * l4);
    float4 x1 = *(const float4*)(qr + kc * 32 + 8 * l4 + 4);
    float4 y0 = *(const float4*)(kr + kc * 32 + 8 * l4);
    float4 y1 = *(const float4*)(kr + kc * 32 + 8 * l4 + 4);
    f16x8 A, K;
    A[0]=(f16)x0.x; A[1]=(f16)x0.y; A[2]=(f16)x0.z; A[3]=(f16)x0.w;
    A[4]=(f16)x1.x; A[5]=(f16)x1.y; A[6]=(f16)x1.z; A[7]=(f16)x1.w;
    K[0]=(f16)y0.x; K[1]=(f16)y0.y; K[2]=(f16)y0.z; K[3]=(f16)y0.w;
    K[4]=(f16)y1.x; K[5]=(f16)y1.y; K[6]=(f16)y1.z; K[7]=(f16)y1.w;
    aq[kc] = A; ak[kc] = K;
  }

  // ---- W -> LDS, transposed + swizzled: elem (r,d) at r*64 + ((d>>3)^(r&7))*8 + (d&7)
  const float* Wqh = Wq + (size_t)h * D_ * R_;
  const float* Wkh = Wk + (size_t)h * D_ * R_;
#pragma unroll
  for (int mm = 0; mm < 2; ++mm) {
    const float* Wh = mm ? Wkh : Wqh;
#pragma unroll
    for (int it = 0; it < 2; ++it) {
      const int flat = it * 1024 + tid * 4;        // = d*32 + r, 4 consecutive r
      const int d = flat >> 5, r = flat & 31;
      const float4 wv = *(const float4*)(Wh + flat);
#pragma unroll
      for (int e = 0; e < 4; ++e) {
        const int rr = r + e;
        s_w[mm][rr * 64 + ((((d >> 3) ^ (rr & 7)) << 3) | (d & 7))] = (f16)((&wv.x)[e]);
      }
    }
  }

#pragma unroll
  for (int it = 0; it < 4; ++it) {
    const int i4 = it * 256 + tid, t = i4 >> 4, dq = (i4 & 15) * 4;
    sv[t * 65 + dq    ] = vld[it].x;
    sv[t * 65 + dq + 1] = vld[it].y;
    sv[t * 65 + dq + 2] = vld[it].z;
    sv[t * 65 + dq + 3] = vld[it].w;
  }

  __syncthreads();   // covers s_w and sv

  f16x8 bq[2][2], bk[2][2];
#pragma unroll
  for (int kc = 0; kc < 2; ++kc)
#pragma unroll
    for (int nt = 0; nt < 2; ++nt) {
      const int r = 16 * nt + l15;
      const int d0 = kc * 32 + 8 * l4;
      const int idx = r * 64 + (((d0 >> 3) ^ (r & 7)) << 3);
      bq[kc][nt] = *(const f16x8*)&s_w[0][idx];
      bk[kc][nt] = *(const f16x8*)&s_w[1][idx];
    }

  const f32x4 z4 = {0.f, 0.f, 0.f, 0.f};
#pragma unroll
  for (int nt = 0; nt < 2; ++nt) {
    f32x4 accq = mfma16(aq[0], bq[0][nt], z4);
    accq = mfma16(aq[1], bq[1][nt], accq);
    f32x4 acck = mfma16(ak[0], bk[0][nt], z4);
    acck = mfma16(ak[1], bk[1][nt], acck);
    const int r = 16 * nt + l15;
    const float scl = c1[h * 4 + (r >> 3)] * c2[h * 8 + (r & 7)] *
                      (0.17677669529663687f * 1.4426950408889634f);
#pragma unroll
    for (int i = 0; i < 4; ++i) {
      const int lrow = 16 * w + 4 * l4 + i;          // local row 0..63
      s_qk[0][lrow * 32 + r] = (f16)(accq[i] * scl);
      s_qk[1][lrow * 32 + r] = (f16)acck[i];
    }
  }

  // vt stores (read sv; safe after first barrier)
#pragma unroll
  for (int it = 0; it < 8; ++it) {
    const int idx = it * 256 + tid, d = idx >> 5, t = (idx & 31) * 2;
    const float f0 = sv[t * 65 + d], f1 = sv[t * 65 + 65 + d];
    f16x2 pr; pr[0] = (f16)f0; pr[1] = (f16)f1;
    const int sw = ((((t >> 3) ^ (d & 7)) << 3) | (t & 7));
    *(f16x2*)(vt + ((size_t)bh * D_ + d) * T_ + t0 + sw) = pr;
  }

  __syncthreads();   // covers s_qk

  const int lrow = tid >> 2;
  const int r0 = (tid & 3) * 8;
  const f16x8 vq = *(const f16x8*)&s_qk[0][lrow * 32 + r0];
  *(f16x8*)(qlr + ((size_t)bh * T_ + t0 + lrow) * R_ + r0) = vq;
  const f16x8 vk = *(const f16x8*)&s_qk[1][lrow * 32 + r0];
  *(f16x8*)(klr + ((size_t)bh * T_ + t0 + lrow) * R_ + r0) = vk;
}

// ---------------- Kernel B: flash attention, 128-col steps, tt-outer LDS ----------------
// R10 post-mortem: LDS pipe is the busiest resource (~60-85%); conflicts rose
// 2.16M->5.01M when s_vt/s_p rows widened 128B->256B. This round: tt-outer
// layouts (s_vt[2][64*64], s_p[w][2][16*64]) restore the R5/R9-proven strides;
// + v_max3-fused max reduce (31->16 ops on the serial chain); + defer-rescale
// (skip exp2 + 16 muls when no row max grew; a==1.0 exactly -> bit-identical).
// m-split only, direct f32 out (R8: no intra-kernel cross-XCD merge).
// No min-waves launch_bounds (R2 spill lesson).
__global__ __launch_bounds__(256) void attn_kernel(
    const f16* __restrict__ qlr, const f16* __restrict__ klr,
    const f16* __restrict__ vt, float* __restrict__ out)
{
  __shared__ __align__(16) f16 s_k[128 * 32];        //  8KB [n][r], n 0..127
  __shared__ __align__(16) f16 s_vt[2][64 * 64];     // 16KB [tt][d][n-swz] (128B rows)
  __shared__ __align__(16) f16 s_p[4][2][16 * 64];   // 16KB per-wave [tt][m][n-swz]

  const int tid = threadIdx.x, w = tid >> 6, lane = tid & 63;
  const int l15 = lane & 15, l4 = lane >> 4;
  const int bh = blockIdx.x & 31;
  const int mt = 31 - (blockIdx.x >> 5);   // longest-first dispatch
  const int m0 = mt * 64;

  // wave w owns m-rows [m0+16w, m0+16w+16); per-lane m = l15 (4 l4-dup groups)
  const f16x8 aq = *(const f16x8*)(qlr + ((size_t)bh * T_ + m0 + 16 * w + l15) * R_ + 8 * l4);

  const f16* kb = klr + (size_t)bh * T_ * R_;
  const f16* vb = vt + (size_t)bh * D_ * T_;

  const f32x4 z4 = {0.f, 0.f, 0.f, 0.f};
  f32x4 oacc[4];
#pragma unroll
  for (int d = 0; d < 4; ++d) oacc[d] = z4;
  float mi = -1e30f, li = 0.f;

  for (int jj = 0; jj <= mt; jj += 2) {
    const int n0 = 64 * jj;                // 128 cols: n0 .. n0+127
    __syncthreads();
    // stage K rows n0..n0+127 (8KB): wave w covers rows 32w..32w+31
#pragma unroll
    for (int e = 0; e < 2; ++e)
      ld_lds16((const char*)kb + (size_t)n0 * 64 + w * 2048 + e * 1024 + lane * 16,
               (char*)s_k + w * 2048 + e * 1024);
    // stage V^T per 64-col tile tt (R9-proven 128B-row layout):
    // wave w covers d = 16w..16w+15 as 2 x (8 rows x 128B) per tile
#pragma unroll
    for (int tt = 0; tt < 2; ++tt)
#pragma unroll
      for (int e = 0; e < 2; ++e) {
        const int d0 = 16 * w + 8 * e;
        ld_lds16((const char*)vb + ((size_t)(d0 + (lane >> 3)) * T_ + n0 + 64 * tt) * 2 + (lane & 7) * 16,
                 (char*)(&s_vt[tt][0]) + d0 * 128);
      }
    __syncthreads();

    // QK^T: sc[ns][i] = score(n_local = 16ns+4l4+i, m = l15), ns 0..7
    f32x4 sc[8];
#pragma unroll
    for (int ns = 0; ns < 8; ++ns) {
      f16x8 akf = *(const f16x8*)&s_k[(16 * ns + l15) * 32 + 8 * l4];
      sc[ns] = mfma16(akf, aq, z4);
    }
    if (jj + 2 > mt) {                      // diagonal (last) iteration
      const int lim = (m0 - n0) + 16 * w + l15;   // mask n_local > lim
#pragma unroll
      for (int ns = 0; ns < 8; ++ns) {
        const int nb = 16 * ns + 4 * l4;
#pragma unroll
        for (int i = 0; i < 4; ++i)
          if (nb + i > lim) sc[ns][i] = -1e30f;
      }
    }

    // row max: pairwise folds -> v_max3 fusion (fmax exact, reorder-safe)
    float rm = fmaxf(sc[0][0], sc[0][1]);
    rm = fmaxf(fmaxf(rm, sc[0][2]), sc[0][3]);
#pragma unroll
    for (int ns = 1; ns < 8; ++ns) {
      rm = fmaxf(fmaxf(rm, sc[ns][0]), sc[ns][1]);
      rm = fmaxf(fmaxf(rm, sc[ns][2]), sc[ns][3]);
    }
    rm = fmaxf(rm, __shfl_xor(rm, 16));
    rm = fmaxf(rm, __shfl_xor(rm, 32));
    const float mn = fmaxf(mi, rm);
    float rs = 0.f;
#pragma unroll
    for (int ns = 0; ns < 8; ++ns) {
      f16x4 pf;
#pragma unroll
      for (int i = 0; i < 4; ++i) {
        const float p = exp2f(sc[ns][i] - mn);
        rs += p; pf[i] = (f16)p;
      }
      // per-tile XOR swizzle (R9 formula), tile tt = ns>>2, local group ns&3
      const int g = ns & 3;
      const int col = ((((2 * g + (l4 >> 1)) ^ (l15 & 7)) << 3) | (4 * (l4 & 1)));
      *(f16x4*)&s_p[w][ns >> 2][l15 * 64 + col] = pf;
    }
    rs += __shfl_xor(rs, 16);
    rs += __shfl_xor(rs, 32);
    if (__any(mn > mi)) {                  // defer-rescale: a==1.0 exactly when skipped
      const float a = exp2f(mi - mn);
      li = li * a + rs;
#pragma unroll
      for (int d = 0; d < 4; ++d) oacc[d] *= a;
    } else {
      li += rs;
    }
    mi = mn;

    // PV over both 64-col tiles: un-swizzle per tile (R9-proven pattern)
#pragma unroll
    for (int tt = 0; tt < 2; ++tt)
#pragma unroll
      for (int nk = 0; nk < 2; ++nk) {
        const int u = (4 * nk + l4) ^ (l15 & 7);
        f16x8 bp = *(const f16x8*)&s_p[w][tt][l15 * 64 + u * 8];
#pragma unroll
        for (int dblk = 0; dblk < 4; ++dblk) {
          f16x8 av = *(const f16x8*)&s_vt[tt][(16 * dblk + l15) * 64 + u * 8];
          oacc[dblk] = mfma16(av, bp, oacc[dblk]);
        }
      }
  }

  // ---- epilogue: final normalize, direct f32 output ----
  const float invl = li > 0.f ? 1.f / li : 0.f;
  float* ob = out + ((size_t)bh * T_ + m0 + 16 * w + l15) * D_;
#pragma unroll
  for (int dblk = 0; dblk < 4; ++dblk) {
    f32x4 o;
#pragma unroll
    for (int i = 0; i < 4; ++i) o[i] = oacc[dblk][i] * invl;
    *(f32x4*)(ob + 16 * dblk + 4 * l4) = o;
  }
}

extern "C" void kernel_launch(void* const* d_in, const int* in_sizes, int n_in,
                              void* d_out, int out_size, void* d_ws, size_t ws_size,
                              hipStream_t stream) {
  const float* q  = (const float*)d_in[0];
  const float* k  = (const float*)d_in[1];
  const float* v  = (const float*)d_in[2];
  const float* Wq = (const float*)d_in[3];
  const float* Wk = (const float*)d_in[4];
  const float* c1 = (const float*)d_in[5];
  const float* c2 = (const float*)d_in[6];
  float* out = (float*)d_out;

  f16* qlr = (f16*)d_ws;                                   // 4 MiB
  f16* klr = qlr + (size_t)B_ * H_ * T_ * R_;              // 4 MiB
  f16* vt  = klr + (size_t)B_ * H_ * T_ * R_;              // 8 MiB

  proj_kernel<<<B_ * H_ * NT, 256, 0, stream>>>(q, k, v, Wq, Wk, c1, c2, qlr, klr, vt);
  attn_kernel<<<B_ * H_ * NT, 256, 0, stream>>>(qlr, klr, vt, out);
}